// Round 2
// baseline (258.772 us; speedup 1.0000x reference)
//
#include <hip/hip_runtime.h>
#include <hip/hip_bf16.h>

// ConvCaps spectral routing.
//   activations[b,o] = sigmoid(lambda_max(G)/tr(G) - bias[o])
//   poses[b,o,:]     = top eigenvector of G, matching LAPACK ssyevd sign conventions.
// R12: SPLIT ONLY (R11 post-mortem: contract(off) changed the recurrence bits ->
// sign flips; the frozen text needs DEFAULT contraction). eig_iter is the R10
// eig_kernel BYTE-VERBATIM from entry through `done:` -- including the in-loop
// LDS rotation log (no store-destination changes inside the frozen region).
// New code is strictly an epilogue after done:: bulk log copy + state dump.
// eig_vec (kmax/replay/back-transform) is continuous in the logged values, so
// it is sign-safe and may be freely optimized in later rounds.
// moments/gram BYTE-VERBATIM R10 (G bits must not move).

#define NSPAT 196

__device__ __forceinline__ float wsum64(float x) {
  x += __shfl_xor(x, 32);
  x += __shfl_xor(x, 16);
  x += __shfl_xor(x, 8);
  x += __shfl_xor(x, 4);
  x += __shfl_xor(x, 2);
  x += __shfl_xor(x, 1);
  return x;
}

// wave-uniform lane read: v_readlane_b32 (SGPR result, no LDS traffic)
__device__ __forceinline__ float rlanef(float x, int i) {
  return __int_as_float(__builtin_amdgcn_readlane(__float_as_int(x), i));
}

// ---------------- kernel A: per-(b,l) moment matrices -----------------------
__global__ __launch_bounds__(256) void moments_kernel(const float* __restrict__ in,
                                                      float* __restrict__ Mout) {
  int b = blockIdx.x >> 5;
  int l = blockIdx.x & 31;
  __shared__ float ps[NSPAT][16];
  __shared__ float as2[NSPAT];
  int t = threadIdx.x;
  const float4* in4 = (const float4*)in;
  for (int j = t; j < NSPAT * 4; j += 256) {
    int s = j >> 2, q = j & 3;
    ((float4*)ps)[j] = in4[(size_t)(b * NSPAT + s) * 136 + l * 4 + q];
  }
  for (int s = t; s < NSPAT; s += 256) {
    float a = in[((size_t)(b * NSPAT + s)) * 544 + 512 + l];
    as2[s] = a * a;
  }
  __syncthreads();
  int p = t >> 4, q = t & 15;
  float acc = 0.f;
  for (int s = 0; s < NSPAT; ++s) {
    // FROZEN TEXT: symmetric-exact accumulation order feeds the eig path bits
    acc += as2[s] * (ps[s][p] * ps[s][q]);
  }
  Mout[(size_t)blockIdx.x * 256 + t] = acc;
}

// ---------------- kernel B: contract moments with weights -> gram ----------
__global__ __launch_bounds__(256) void gram_kernel(const float* __restrict__ Min,
                                                   const float* __restrict__ W,
                                                   float* __restrict__ Gout) {
  int b = blockIdx.x >> 5;
  int o = blockIdx.x & 31;
  int t = threadIdx.x;
  __shared__ float Ms[32][256];
  __shared__ float Ws[32][16];
  const float4* Min4 = (const float4*)Min;
  const float4* W4 = (const float4*)W;
  for (int j = t; j < 2048; j += 256)
    ((float4*)Ms)[j] = Min4[(size_t)b * 2048 + j];
  for (int j = t; j < 128; j += 256) {
    int l = j >> 2, q = j & 3;
    ((float4*)Ws)[j] = W4[(size_t)(l * 32 + o) * 4 + q];
  }
  __syncthreads();
  int p = t >> 4, q = t & 15;
  int i1 = p >> 2, k1 = p & 3, i2 = q >> 2, k2 = q & 3;
  float acc = 0.f;
  for (int l = 0; l < 32; ++l) {
    float sub = 0.f;
    for (int j2 = 0; j2 < 4; ++j2) {
      float inner = 0.f;
      for (int j = 0; j < 4; ++j)
        inner += Ws[l][j * 4 + k1] * Ms[l][(i1 * 4 + j) * 16 + (i2 * 4 + j2)];
      sub += Ws[l][j2 * 4 + k2] * inner;
    }
    acc += sub;
  }
  Gout[(size_t)blockIdx.x * 256 + t] = acc;
}

// ---------------- LAPACK fp32 helpers (sign-faithful, FROZEN TEXT) ---------
#define EPSF    5.9604645e-08f   /* slamch('E') = 2^-24 */
#define EPS2F   (EPSF * EPSF)
#define SAFMINF 1.1754944e-38f   /* slamch('S') */

__device__ __forceinline__ float ssign(float a, float b) {
  return (b >= 0.f) ? fabsf(a) : -fabsf(a);
}

__device__ __forceinline__ float slapy2(float x, float y) {
  float xa = fabsf(x), ya = fabsf(y);
  float w = fmaxf(xa, ya), z = fminf(xa, ya);
  if (z == 0.f) return w;
  float t = z / w;
  return w * sqrtf(1.f + t * t);
}

// LAPACK >= 3.10 slartg convention (c >= 0, r carries sign of f)
__device__ __forceinline__ void slartg(float f, float g, float* c, float* s, float* r) {
  if (g == 0.f) {
    *c = 1.f; *s = 0.f; *r = f;
  } else if (f == 0.f) {
    *c = 0.f; *s = (g >= 0.f) ? 1.f : -1.f; *r = fabsf(g);
  } else {
    float d = sqrtf(f * f + g * g);
    *c = fabsf(f) / d;
    float rr = (f >= 0.f) ? d : -d;
    *s = g / rr;
    *r = rr;
  }
}

__device__ __forceinline__ void slaev2(float a, float b, float c,
                                       float* rt1, float* rt2, float* cs1, float* sn1) {
  float sm = a + c;
  float df = a - c;
  float adf = fabsf(df);
  float tb = b + b;
  float ab = fabsf(tb);
  float acmx, acmn;
  if (fabsf(a) > fabsf(c)) { acmx = a; acmn = c; } else { acmx = c; acmn = a; }
  float rt;
  if (adf > ab)      { float t = ab / adf; rt = adf * sqrtf(1.f + t * t); }
  else if (adf < ab) { float t = adf / ab; rt = ab * sqrtf(1.f + t * t); }
  else               { rt = ab * sqrtf(2.f); }
  int sgn1;
  if (sm < 0.f) {
    *rt1 = 0.5f * (sm - rt); sgn1 = -1;
    *rt2 = (acmx / *rt1) * acmn - (b / *rt1) * b;
  } else if (sm > 0.f) {
    *rt1 = 0.5f * (sm + rt); sgn1 = 1;
    *rt2 = (acmx / *rt1) * acmn - (b / *rt1) * b;
  } else {
    *rt1 = 0.5f * rt; *rt2 = -0.5f * rt; sgn1 = 1;
  }
  float cs; int sgn2;
  if (df >= 0.f) { cs = df + rt; sgn2 = 1; }
  else           { cs = df - rt; sgn2 = -1; }
  float acs = fabsf(cs);
  float c1, s1;
  if (acs > ab) {
    float ct = -tb / cs;
    s1 = 1.f / sqrtf(1.f + ct * ct);
    c1 = ct * s1;
  } else {
    if (ab == 0.f) { c1 = 1.f; s1 = 0.f; }
    else {
      float tn = -cs / tb;
      c1 = 1.f / sqrtf(1.f + tn * tn);
      s1 = tn * c1;
    }
  }
  if (sgn1 == sgn2) { float tn = c1; c1 = -s1; s1 = tn; }
  *cs1 = c1; *sn1 = s1;
}

#define MAXLOG 1024

// ---------------- kernel C1: recurrence (FROZEN through done:) -------------
// Entry through `done:` is BYTE-VERBATIM the R10 eig_kernel (in-loop LDS log
// stores untouched). Only the post-done epilogue is new: dump log + state.
__global__ __launch_bounds__(64) void eig_iter_kernel(const float* __restrict__ G,
                                                      float2* __restrict__ glogcs,
                                                      int* __restrict__ glogi,
                                                      float* __restrict__ gA,
                                                      float* __restrict__ gtau,
                                                      float* __restrict__ gd,
                                                      float* __restrict__ gtrace,
                                                      int* __restrict__ gnrot) {
  const int pid = blockIdx.x;   // b*32 + o
  const int lane = threadIdx.x;
  const int row = lane & 15;
  __shared__ float A[16][17];      // working matrix / householder vectors
  __shared__ float ddl[64][17];    // per-lane replicated d
  __shared__ float eel[64][17];    // per-lane replicated e
  __shared__ float ttl[64][17];    // per-lane replicated tau
  __shared__ float2 logcs[MAXLOG]; // rotation log: (c, sigma)
  __shared__ int    logi[MAXLOG];  // rotation log: column index i

  // load + symmetrize (use lower triangle)
  for (int k = 0; k < 4; ++k) {
    int t = lane + 64 * k;
    int r = t >> 4, c = t & 15;
    int rr = r >= c ? r : c;
    int cc = r >= c ? c : r;
    A[r][c] = G[(size_t)pid * 256 + rr * 16 + cc];
  }
  float trc = (lane < 16) ? G[(size_t)pid * 256 + lane * 17] : 0.f;
  float trace = wsum64(trc);
  __syncthreads();

  // ---- ssytd2 (lower) ----
  for (int i = 0; i < 15; ++i) {
    float acol = (lane < 16) ? A[lane][i] : 0.f;
    float alpha = __shfl(acol, i + 1);
    float x = (lane >= i + 2 && lane < 16) ? acol : 0.f;
    float xns = wsum64(x * x);
    if (xns == 0.f) {
      eel[lane][i] = alpha;
      ttl[lane][i] = 0.f;
      continue;
    }
    float beta = (alpha >= 0.f ? -1.f : 1.f) * sqrtf(alpha * alpha + xns);
    float taui = (beta - alpha) / beta;
    float scal = 1.f / (alpha - beta);
    float vreg = 0.f;
    if (lane == i + 1) vreg = 1.f;
    else if (lane >= i + 2 && lane < 16) {
      vreg = acol * scal;
      A[lane][i] = vreg;   // persist householder vector (lane-local write)
    }
    eel[lane][i] = beta;
    ttl[lane][i] = taui;
    float wr = 0.f;
    for (int cI = i + 1; cI < 16; ++cI) {
      float vc = __shfl(vreg, cI);
      if (lane >= i + 1 && lane < 16) wr += A[lane][cI] * vc;
    }
    wr *= taui;
    float dot = wsum64((lane >= i + 1 && lane < 16) ? wr * vreg : 0.f);
    float alpha2 = -0.5f * taui * dot;
    wr += alpha2 * vreg;
    for (int cI = i + 1; cI < 16; ++cI) {
      float wc = __shfl(wr, cI);
      float vc = __shfl(vreg, cI);
      if (lane >= i + 1 && lane < 16) A[lane][cI] -= vreg * wc + wr * vc;
    }
  }

  // gather d into per-lane replicated arrays
  float di = (lane < 16) ? A[lane][lane] : 0.f;
  for (int j = 0; j < 16; ++j) ddl[lane][j] = __shfl(di, j);

  float* dd = ddl[lane];
  float* ee = eel[lane];
  ee[15] = 0.f;   // pad slot for snapshots

  // ---- ssteqr('I') ----
  int m, l, lsv, lend, lendsv;
  int jtot = 0;
  const int nmaxit = 16 * 30;
  int l1 = 0;
  int nrot = 0;
  float dsn, esn;   // snapshots: lane j holds d[j] / e[j]

outer:
  if (l1 > 15) goto done;
  if (l1 > 0) ee[l1 - 1] = 0.f;
  dsn = dd[row];   // outer-top snapshot (after the e zeroing above)
  esn = ee[row];
  {
    int mm;
    for (mm = l1; mm < 15; ++mm) {
      float eI = rlanef(esn, mm);
      float tst = fabsf(eI);
      if (tst == 0.f) break;
      if (tst <= (sqrtf(fabsf(rlanef(dsn, mm))) * sqrtf(fabsf(rlanef(dsn, mm + 1)))) * EPSF) {
        ee[mm] = 0.f;
        break;
      }
    }
    m = mm;
  }
  l = l1; lsv = l; lend = m; lendsv = lend;
  l1 = m + 1;
  if (lend == l) goto outer;
  {
    // anorm over [l, lend] (the scan's ee[m]=0 write is outside this range)
    float an = 0.f;
    for (int k2 = l; k2 <= lend; ++k2) an = fmaxf(an, fabsf(rlanef(dsn, k2)));
    for (int k2 = l; k2 < lend; ++k2) an = fmaxf(an, fabsf(rlanef(esn, k2)));
    if (an == 0.f) goto outer;
  }
  if (fabsf(rlanef(dsn, lend)) < fabsf(rlanef(dsn, l))) { lend = lsv; l = lendsv; }

  if (lend > l) {
    // ----- QL -----
ql_top:
    dsn = dd[row];   // refresh snapshot (pre-sweep values)
    esn = ee[row];
    {
      int mm;
      for (mm = l; mm < lend; ++mm) {
        float eI = rlanef(esn, mm);
        float tst = eI * eI;
        if (tst <= (EPS2F * fabsf(rlanef(dsn, mm))) * fabsf(rlanef(dsn, mm + 1)) + SAFMINF) break;
      }
      m = mm;
    }
    if (m < lend) ee[m] = 0.f;   // pre-snapshot reads below all use idx < m
    {
      float p = rlanef(dsn, l);
      if (m == l) {
        dd[l] = p;
        l = l + 1;
        if (l <= lend) goto ql_top;
        goto blk_done;
      }
      if (m == l + 1) {
        float rt1, rt2, c2, s2;
        slaev2(rlanef(dsn, l), rlanef(esn, l), rlanef(dsn, l + 1), &rt1, &rt2, &c2, &s2);
        if (lane == 0 && nrot < MAXLOG) { logcs[nrot] = make_float2(c2, -s2); logi[nrot] = l; }
        nrot++;
        dd[l] = rt1; dd[l + 1] = rt2; ee[l] = 0.f;
        l += 2;
        if (l <= lend) goto ql_top;
        goto blk_done;
      }
      if (jtot == nmaxit) goto blk_done;
      jtot++;
      float g = (rlanef(dsn, l + 1) - p) / (2.f * rlanef(esn, l));
      float r = slapy2(g, 1.f);
      g = rlanef(dsn, m) - p + rlanef(esn, l) / (g + ssign(r, g));
      float s = 1.f, c = 1.f;
      p = 0.f;
      for (int i = m - 1; i >= l; --i) {
        float eI = rlanef(esn, i);
        float f = s * eI;
        float bb = c * eI;
        slartg(g, f, &c, &s, &r);
        if (i != m - 1) ee[i + 1] = r;
        g = rlanef(dsn, i + 1) - p;
        r = (rlanef(dsn, i) - g) * s + 2.f * c * bb;
        p = s * r;
        dd[i + 1] = g + p;
        g = c * r - bb;
        if (lane == 0 && nrot < MAXLOG) { logcs[nrot] = make_float2(c, s); logi[nrot] = i; }  // QL: sigma=+s
        nrot++;
      }
      dd[l] = rlanef(dsn, l) - p;   // d[l] untouched by sweep writes
      ee[l] = g;
    }
    goto ql_top;
  } else {
    // ----- QR -----
qr_top:
    dsn = dd[row];
    esn = ee[row];
    {
      int mm;
      for (mm = l; mm > lend; --mm) {
        float eI = rlanef(esn, mm - 1);
        float tst = eI * eI;
        if (tst <= (EPS2F * fabsf(rlanef(dsn, mm))) * fabsf(rlanef(dsn, mm - 1)) + SAFMINF) break;
      }
      m = mm;
    }
    if (m > lend) ee[m - 1] = 0.f;
    {
      float p = rlanef(dsn, l);
      if (m == l) {
        dd[l] = p;
        l = l - 1;
        if (l >= lend) goto qr_top;
        goto blk_done;
      }
      if (m == l - 1) {
        float rt1, rt2, c2, s2;
        slaev2(rlanef(dsn, l - 1), rlanef(esn, l - 1), rlanef(dsn, l), &rt1, &rt2, &c2, &s2);
        if (lane == 0 && nrot < MAXLOG) { logcs[nrot] = make_float2(c2, -s2); logi[nrot] = l - 1; }
        nrot++;
        dd[l - 1] = rt1; dd[l] = rt2; ee[l - 1] = 0.f;
        l -= 2;
        if (l >= lend) goto qr_top;
        goto blk_done;
      }
      if (jtot == nmaxit) goto blk_done;
      jtot++;
      float g = (rlanef(dsn, l - 1) - p) / (2.f * rlanef(esn, l - 1));
      float r = slapy2(g, 1.f);
      g = rlanef(dsn, m) - p + rlanef(esn, l - 1) / (g + ssign(r, g));
      float s = 1.f, c = 1.f;
      p = 0.f;
      for (int i = m; i <= l - 1; ++i) {
        float eI = rlanef(esn, i);
        float f = s * eI;
        float bb = c * eI;
        slartg(g, f, &c, &s, &r);
        if (i != m) ee[i - 1] = r;
        g = rlanef(dsn, i) - p;
        r = (rlanef(dsn, i + 1) - g) * s + 2.f * c * bb;
        p = s * r;
        dd[i] = g + p;
        g = c * r - bb;
        if (lane == 0 && nrot < MAXLOG) { logcs[nrot] = make_float2(c, -s); logi[nrot] = i; }  // QR: sigma=-s
        nrot++;
      }
      dd[l] = rlanef(dsn, l) - p;
      ee[l - 1] = g;
    }
    goto qr_top;
  }
blk_done:
  goto outer;

done:;
  // -------- NEW epilogue (outside the frozen region): dump state ----------
  if (lane < 16) gd[(size_t)pid * 16 + lane] = ddl[lane][lane];
  if (lane < 16) gtau[(size_t)pid * 16 + lane] = (lane < 15) ? ttl[lane][lane] : 0.f;
  for (int k = 0; k < 4; ++k) {
    int t = lane + 64 * k;
    int r = t >> 4, c = t & 15;
    gA[(size_t)pid * 256 + r * 16 + c] = A[r][c];
  }
  if (lane == 0) { gnrot[pid] = nrot; gtrace[pid] = trace; }
  int ncap = nrot < MAXLOG ? nrot : MAXLOG;
  for (int j = lane; j < ncap; j += 64) {
    glogcs[(size_t)pid * MAXLOG + j] = logcs[j];
    glogi[(size_t)pid * MAXLOG + j] = logi[j];
  }
}

// ---------------- kernel C2: kmax + reverse replay + back-transform --------
// Sign-safe: all arithmetic here is continuous in the (bit-exact) logged
// rotations, d, tau, A. Free to optimize in later rounds.
__global__ __launch_bounds__(64) void eig_vec_kernel(const float2* __restrict__ glogcs,
                                                     const int* __restrict__ glogi,
                                                     const float* __restrict__ gA,
                                                     const float* __restrict__ gtau,
                                                     const float* __restrict__ gd,
                                                     const float* __restrict__ gtrace,
                                                     const int* __restrict__ gnrot,
                                                     const float* __restrict__ bias,
                                                     float* __restrict__ out) {
  const int pid = blockIdx.x;   // b*32 + o
  const int lane = threadIdx.x;
  __shared__ float A[16][17];
  __shared__ float taus[16];

  for (int k = 0; k < 4; ++k) {
    int t = lane + 64 * k;
    int r = t >> 4, c = t & 15;
    A[r][c] = gA[(size_t)pid * 256 + r * 16 + c];
  }
  if (lane < 16) taus[lane] = gtau[(size_t)pid * 16 + lane];
  float dsn = (lane < 16) ? gd[(size_t)pid * 16 + lane] : 0.f;  // lane j holds d[j]
  int nrot = gnrot[pid];
  float trace = gtrace[pid];
  __syncthreads();

  // top eigenvalue index
  int kmax = 0;
  float dmax = rlanef(dsn, 0);
  for (int j = 1; j < 16; ++j) {
    float dj = rlanef(dsn, j);
    if (dj > dmax) { dmax = dj; kmax = j; }
  }

  // reconstruct v = Z[:,kmax] by reverse replay: w = G_0(G_1(...(G_{n-1} e_kmax)))
  //   (G*w)[i] = c*w[i] + sg*w[i+1]; (G*w)[i+1] = -sg*w[i] + c*w[i+1]
  float w = (lane == kmax) ? 1.f : 0.f;
  {
    int t = nrot - 1;
    if (t > MAXLOG - 1) t = MAXLOG - 1;   // (overflow cannot happen for sane inputs)
    while (t >= 0) {
      int base = t & ~63;
      float2 cs = glogcs[(size_t)pid * MAXLOG + base + lane];   // lane k holds entry base+k
      int ii = glogi[(size_t)pid * MAXLOG + base + lane];
      for (int k = t - base; k >= 0; --k) {
        float c = rlanef(cs.x, k);
        float sg = rlanef(cs.y, k);
        int i = __builtin_amdgcn_readlane(ii, k);
        float wup = __shfl_up(w, 1);
        float wdn = __shfl_down(w, 1);
        float nw = w;
        if (lane == i) nw = c * w + sg * wdn;
        else if (lane == i + 1) nw = -sg * wup + c * w;
        w = nw;
      }
      t = base - 1;
    }
  }

  float vreg = (lane < 16) ? w : 0.f;
  // back-transform: v := H(0) H(1) ... H(14) v  (apply H(14) first)
  for (int i = 14; i >= 0; --i) {
    float taui = taus[i];
    if (taui == 0.f) continue;
    float contrib;
    if (lane == i + 1) contrib = vreg;
    else if (lane >= i + 2 && lane < 16) contrib = A[lane][i] * vreg;
    else contrib = 0.f;
    float dot = wsum64(contrib);
    float td = taui * dot;
    if (lane == i + 1) vreg -= td;
    else if (lane >= i + 2 && lane < 16) vreg -= td * A[lane][i];
  }

  float act = 1.f / (1.f + expf(-(dmax / trace - bias[pid & 31])));
  if (lane == 0) out[pid] = act;
  if (lane < 16) out[512 + pid * 16 + lane] = vreg;
}

extern "C" void kernel_launch(void* const* d_in, const int* in_sizes, int n_in,
                              void* d_out, int out_size, void* d_ws, size_t ws_size,
                              hipStream_t stream) {
  const float* in   = (const float*)d_in[0];   // [16,14,14,544] fp32
  const float* W    = (const float*)d_in[1];   // [1,32,32,4,4] fp32
  const float* bias = (const float*)d_in[2];   // [32] fp32
  float* out = (float*)d_out;

  // workspace layout (~7.6 MB total)
  float* Mbuf = (float*)d_ws;                          // 512*256 f = 512 KB
  float* Gbuf = Mbuf + 512 * 256;                      // 512*256 f = 512 KB
  float2* glogcs = (float2*)(Gbuf + 512 * 256);        // 512*1024 float2 = 4 MB
  int* glogi = (int*)(glogcs + 512 * MAXLOG);          // 512*1024 int = 2 MB
  float* gA   = (float*)(glogi + 512 * MAXLOG);        // 512*256 f = 512 KB
  float* gtau = gA + 512 * 256;                        // 512*16 f = 32 KB
  float* gd   = gtau + 512 * 16;                       // 512*16 f = 32 KB
  float* gtrace = gd + 512 * 16;                       // 512 f = 2 KB
  int*   gnrot = (int*)(gtrace + 512);                 // 512 int = 2 KB

  moments_kernel<<<512, 256, 0, stream>>>(in, Mbuf);
  gram_kernel<<<512, 256, 0, stream>>>(Mbuf, W, Gbuf);
  eig_iter_kernel<<<512, 64, 0, stream>>>(Gbuf, glogcs, glogi, gA, gtau, gd, gtrace, gnrot);
  eig_vec_kernel<<<512, 64, 0, stream>>>(glogcs, glogi, gA, gtau, gd, gtrace, gnrot, bias, out);
}

// Round 3
// 246.898 us; speedup vs baseline: 1.0481x; 1.0481x over previous
//
#include <hip/hip_runtime.h>
#include <hip/hip_bf16.h>

// ConvCaps spectral routing.
//   activations[b,o] = sigmoid(lambda_max(G)/tr(G) - bias[o])
//   poses[b,o,:]     = top eigenvector of G, matching LAPACK ssyevd sign conventions.
// R13: monolith again (drop R12's global log round-trip), with a REWRITTEN
// sign-safe replay epilogue:
//   - DPP row_shl/row_shr adjacent-lane exchange (VALU ~4cy) replaces
//     __shfl_up/__shfl_down (LDS-pipe ~35cy) on the serial w-chain.
//   - rotation log padded to a multiple of 64 with i=255 sentinels (no lane
//     matches -> w untouched, zero FP ops on padding), so the inner 64-batch
//     loop is compile-time unrolled with uniform-address LDS broadcast loads.
// R12 proved epilogue-after-done: edits do not perturb the frozen region's
// codegen (decision bits unchanged). Everything through done: is BYTE-VERBATIM
// R10/R12 frozen text. moments/gram BYTE-VERBATIM (G bits must not move).

#define NSPAT 196

__device__ __forceinline__ float wsum64(float x) {
  x += __shfl_xor(x, 32);
  x += __shfl_xor(x, 16);
  x += __shfl_xor(x, 8);
  x += __shfl_xor(x, 4);
  x += __shfl_xor(x, 2);
  x += __shfl_xor(x, 1);
  return x;
}

// wave-uniform lane read: v_readlane_b32 (SGPR result, no LDS traffic)
__device__ __forceinline__ float rlanef(float x, int i) {
  return __int_as_float(__builtin_amdgcn_readlane(__float_as_int(x), i));
}

// DPP adjacent exchanges within 16-lane rows (VALU latency, no LDS pipe).
// dpp_shl1: lane i reads lane i+1 (ROW_SHL:1 = 0x101)  [__shfl_down(x,1)]
// dpp_shr1: lane i reads lane i-1 (ROW_SHR:1 = 0x111)  [__shfl_up(x,1)]
// Row-edge lanes get 0 (bound_ctrl) — only consumed by lanes that never
// match the rotation index, so don't-care.
__device__ __forceinline__ float dpp_shl1(float x) {
  return __int_as_float(__builtin_amdgcn_update_dpp(0, __float_as_int(x), 0x101, 0xf, 0xf, true));
}
__device__ __forceinline__ float dpp_shr1(float x) {
  return __int_as_float(__builtin_amdgcn_update_dpp(0, __float_as_int(x), 0x111, 0xf, 0xf, true));
}

// ---------------- kernel A: per-(b,l) moment matrices -----------------------
__global__ __launch_bounds__(256) void moments_kernel(const float* __restrict__ in,
                                                      float* __restrict__ Mout) {
  int b = blockIdx.x >> 5;
  int l = blockIdx.x & 31;
  __shared__ float ps[NSPAT][16];
  __shared__ float as2[NSPAT];
  int t = threadIdx.x;
  const float4* in4 = (const float4*)in;
  for (int j = t; j < NSPAT * 4; j += 256) {
    int s = j >> 2, q = j & 3;
    ((float4*)ps)[j] = in4[(size_t)(b * NSPAT + s) * 136 + l * 4 + q];
  }
  for (int s = t; s < NSPAT; s += 256) {
    float a = in[((size_t)(b * NSPAT + s)) * 544 + 512 + l];
    as2[s] = a * a;
  }
  __syncthreads();
  int p = t >> 4, q = t & 15;
  float acc = 0.f;
  for (int s = 0; s < NSPAT; ++s) {
    // FROZEN TEXT: symmetric-exact accumulation order feeds the eig path bits
    acc += as2[s] * (ps[s][p] * ps[s][q]);
  }
  Mout[(size_t)blockIdx.x * 256 + t] = acc;
}

// ---------------- kernel B: contract moments with weights -> gram ----------
__global__ __launch_bounds__(256) void gram_kernel(const float* __restrict__ Min,
                                                   const float* __restrict__ W,
                                                   float* __restrict__ Gout) {
  int b = blockIdx.x >> 5;
  int o = blockIdx.x & 31;
  int t = threadIdx.x;
  __shared__ float Ms[32][256];
  __shared__ float Ws[32][16];
  const float4* Min4 = (const float4*)Min;
  const float4* W4 = (const float4*)W;
  for (int j = t; j < 2048; j += 256)
    ((float4*)Ms)[j] = Min4[(size_t)b * 2048 + j];
  for (int j = t; j < 128; j += 256) {
    int l = j >> 2, q = j & 3;
    ((float4*)Ws)[j] = W4[(size_t)(l * 32 + o) * 4 + q];
  }
  __syncthreads();
  int p = t >> 4, q = t & 15;
  int i1 = p >> 2, k1 = p & 3, i2 = q >> 2, k2 = q & 3;
  float acc = 0.f;
  for (int l = 0; l < 32; ++l) {
    float sub = 0.f;
    for (int j2 = 0; j2 < 4; ++j2) {
      float inner = 0.f;
      for (int j = 0; j < 4; ++j)
        inner += Ws[l][j * 4 + k1] * Ms[l][(i1 * 4 + j) * 16 + (i2 * 4 + j2)];
      sub += Ws[l][j2 * 4 + k2] * inner;
    }
    acc += sub;
  }
  Gout[(size_t)blockIdx.x * 256 + t] = acc;
}

// ---------------- LAPACK fp32 helpers (sign-faithful, FROZEN TEXT) ---------
#define EPSF    5.9604645e-08f   /* slamch('E') = 2^-24 */
#define EPS2F   (EPSF * EPSF)
#define SAFMINF 1.1754944e-38f   /* slamch('S') */

__device__ __forceinline__ float ssign(float a, float b) {
  return (b >= 0.f) ? fabsf(a) : -fabsf(a);
}

__device__ __forceinline__ float slapy2(float x, float y) {
  float xa = fabsf(x), ya = fabsf(y);
  float w = fmaxf(xa, ya), z = fminf(xa, ya);
  if (z == 0.f) return w;
  float t = z / w;
  return w * sqrtf(1.f + t * t);
}

// LAPACK >= 3.10 slartg convention (c >= 0, r carries sign of f)
__device__ __forceinline__ void slartg(float f, float g, float* c, float* s, float* r) {
  if (g == 0.f) {
    *c = 1.f; *s = 0.f; *r = f;
  } else if (f == 0.f) {
    *c = 0.f; *s = (g >= 0.f) ? 1.f : -1.f; *r = fabsf(g);
  } else {
    float d = sqrtf(f * f + g * g);
    *c = fabsf(f) / d;
    float rr = (f >= 0.f) ? d : -d;
    *s = g / rr;
    *r = rr;
  }
}

__device__ __forceinline__ void slaev2(float a, float b, float c,
                                       float* rt1, float* rt2, float* cs1, float* sn1) {
  float sm = a + c;
  float df = a - c;
  float adf = fabsf(df);
  float tb = b + b;
  float ab = fabsf(tb);
  float acmx, acmn;
  if (fabsf(a) > fabsf(c)) { acmx = a; acmn = c; } else { acmx = c; acmn = a; }
  float rt;
  if (adf > ab)      { float t = ab / adf; rt = adf * sqrtf(1.f + t * t); }
  else if (adf < ab) { float t = adf / ab; rt = ab * sqrtf(1.f + t * t); }
  else               { rt = ab * sqrtf(2.f); }
  int sgn1;
  if (sm < 0.f) {
    *rt1 = 0.5f * (sm - rt); sgn1 = -1;
    *rt2 = (acmx / *rt1) * acmn - (b / *rt1) * b;
  } else if (sm > 0.f) {
    *rt1 = 0.5f * (sm + rt); sgn1 = 1;
    *rt2 = (acmx / *rt1) * acmn - (b / *rt1) * b;
  } else {
    *rt1 = 0.5f * rt; *rt2 = -0.5f * rt; sgn1 = 1;
  }
  float cs; int sgn2;
  if (df >= 0.f) { cs = df + rt; sgn2 = 1; }
  else           { cs = df - rt; sgn2 = -1; }
  float acs = fabsf(cs);
  float c1, s1;
  if (acs > ab) {
    float ct = -tb / cs;
    s1 = 1.f / sqrtf(1.f + ct * ct);
    c1 = ct * s1;
  } else {
    if (ab == 0.f) { c1 = 1.f; s1 = 0.f; }
    else {
      float tn = -cs / tb;
      c1 = 1.f / sqrtf(1.f + tn * tn);
      s1 = tn * c1;
    }
  }
  if (sgn1 == sgn2) { float tn = c1; c1 = -s1; s1 = tn; }
  *cs1 = c1; *sn1 = s1;
}

#define MAXLOG 1024

// ---------------- kernel C: one wave per 16x16 eig problem -----------------
// Entry through `done:` is BYTE-VERBATIM the R10/R12 frozen recurrence
// (in-loop LDS log stores untouched). Epilogue after done: is the new
// sign-safe fast replay (DPP + padded unrolled batches).
__global__ __launch_bounds__(64) void eig_kernel(const float* __restrict__ G,
                                                 const float* __restrict__ bias,
                                                 float* __restrict__ out) {
  const int pid = blockIdx.x;   // b*32 + o
  const int lane = threadIdx.x;
  const int row = lane & 15;
  __shared__ float A[16][17];      // working matrix / householder vectors
  __shared__ float ddl[64][17];    // per-lane replicated d
  __shared__ float eel[64][17];    // per-lane replicated e
  __shared__ float ttl[64][17];    // per-lane replicated tau
  __shared__ float2 logcs[MAXLOG]; // rotation log: (c, sigma)
  __shared__ int    logi[MAXLOG];  // rotation log: column index i

  // load + symmetrize (use lower triangle)
  for (int k = 0; k < 4; ++k) {
    int t = lane + 64 * k;
    int r = t >> 4, c = t & 15;
    int rr = r >= c ? r : c;
    int cc = r >= c ? c : r;
    A[r][c] = G[(size_t)pid * 256 + rr * 16 + cc];
  }
  float trc = (lane < 16) ? G[(size_t)pid * 256 + lane * 17] : 0.f;
  float trace = wsum64(trc);
  __syncthreads();

  // ---- ssytd2 (lower) ----
  for (int i = 0; i < 15; ++i) {
    float acol = (lane < 16) ? A[lane][i] : 0.f;
    float alpha = __shfl(acol, i + 1);
    float x = (lane >= i + 2 && lane < 16) ? acol : 0.f;
    float xns = wsum64(x * x);
    if (xns == 0.f) {
      eel[lane][i] = alpha;
      ttl[lane][i] = 0.f;
      continue;
    }
    float beta = (alpha >= 0.f ? -1.f : 1.f) * sqrtf(alpha * alpha + xns);
    float taui = (beta - alpha) / beta;
    float scal = 1.f / (alpha - beta);
    float vreg = 0.f;
    if (lane == i + 1) vreg = 1.f;
    else if (lane >= i + 2 && lane < 16) {
      vreg = acol * scal;
      A[lane][i] = vreg;   // persist householder vector (lane-local write)
    }
    eel[lane][i] = beta;
    ttl[lane][i] = taui;
    float wr = 0.f;
    for (int cI = i + 1; cI < 16; ++cI) {
      float vc = __shfl(vreg, cI);
      if (lane >= i + 1 && lane < 16) wr += A[lane][cI] * vc;
    }
    wr *= taui;
    float dot = wsum64((lane >= i + 1 && lane < 16) ? wr * vreg : 0.f);
    float alpha2 = -0.5f * taui * dot;
    wr += alpha2 * vreg;
    for (int cI = i + 1; cI < 16; ++cI) {
      float wc = __shfl(wr, cI);
      float vc = __shfl(vreg, cI);
      if (lane >= i + 1 && lane < 16) A[lane][cI] -= vreg * wc + wr * vc;
    }
  }

  // gather d into per-lane replicated arrays
  float di = (lane < 16) ? A[lane][lane] : 0.f;
  for (int j = 0; j < 16; ++j) ddl[lane][j] = __shfl(di, j);

  float* dd = ddl[lane];
  float* ee = eel[lane];
  ee[15] = 0.f;   // pad slot for snapshots

  // ---- ssteqr('I') ----
  int m, l, lsv, lend, lendsv;
  int jtot = 0;
  const int nmaxit = 16 * 30;
  int l1 = 0;
  int nrot = 0;
  float dsn, esn;   // snapshots: lane j holds d[j] / e[j]

outer:
  if (l1 > 15) goto done;
  if (l1 > 0) ee[l1 - 1] = 0.f;
  dsn = dd[row];   // outer-top snapshot (after the e zeroing above)
  esn = ee[row];
  {
    int mm;
    for (mm = l1; mm < 15; ++mm) {
      float eI = rlanef(esn, mm);
      float tst = fabsf(eI);
      if (tst == 0.f) break;
      if (tst <= (sqrtf(fabsf(rlanef(dsn, mm))) * sqrtf(fabsf(rlanef(dsn, mm + 1)))) * EPSF) {
        ee[mm] = 0.f;
        break;
      }
    }
    m = mm;
  }
  l = l1; lsv = l; lend = m; lendsv = lend;
  l1 = m + 1;
  if (lend == l) goto outer;
  {
    // anorm over [l, lend] (the scan's ee[m]=0 write is outside this range)
    float an = 0.f;
    for (int k2 = l; k2 <= lend; ++k2) an = fmaxf(an, fabsf(rlanef(dsn, k2)));
    for (int k2 = l; k2 < lend; ++k2) an = fmaxf(an, fabsf(rlanef(esn, k2)));
    if (an == 0.f) goto outer;
  }
  if (fabsf(rlanef(dsn, lend)) < fabsf(rlanef(dsn, l))) { lend = lsv; l = lendsv; }

  if (lend > l) {
    // ----- QL -----
ql_top:
    dsn = dd[row];   // refresh snapshot (pre-sweep values)
    esn = ee[row];
    {
      int mm;
      for (mm = l; mm < lend; ++mm) {
        float eI = rlanef(esn, mm);
        float tst = eI * eI;
        if (tst <= (EPS2F * fabsf(rlanef(dsn, mm))) * fabsf(rlanef(dsn, mm + 1)) + SAFMINF) break;
      }
      m = mm;
    }
    if (m < lend) ee[m] = 0.f;   // pre-snapshot reads below all use idx < m
    {
      float p = rlanef(dsn, l);
      if (m == l) {
        dd[l] = p;
        l = l + 1;
        if (l <= lend) goto ql_top;
        goto blk_done;
      }
      if (m == l + 1) {
        float rt1, rt2, c2, s2;
        slaev2(rlanef(dsn, l), rlanef(esn, l), rlanef(dsn, l + 1), &rt1, &rt2, &c2, &s2);
        if (lane == 0 && nrot < MAXLOG) { logcs[nrot] = make_float2(c2, -s2); logi[nrot] = l; }
        nrot++;
        dd[l] = rt1; dd[l + 1] = rt2; ee[l] = 0.f;
        l += 2;
        if (l <= lend) goto ql_top;
        goto blk_done;
      }
      if (jtot == nmaxit) goto blk_done;
      jtot++;
      float g = (rlanef(dsn, l + 1) - p) / (2.f * rlanef(esn, l));
      float r = slapy2(g, 1.f);
      g = rlanef(dsn, m) - p + rlanef(esn, l) / (g + ssign(r, g));
      float s = 1.f, c = 1.f;
      p = 0.f;
      for (int i = m - 1; i >= l; --i) {
        float eI = rlanef(esn, i);
        float f = s * eI;
        float bb = c * eI;
        slartg(g, f, &c, &s, &r);
        if (i != m - 1) ee[i + 1] = r;
        g = rlanef(dsn, i + 1) - p;
        r = (rlanef(dsn, i) - g) * s + 2.f * c * bb;
        p = s * r;
        dd[i + 1] = g + p;
        g = c * r - bb;
        if (lane == 0 && nrot < MAXLOG) { logcs[nrot] = make_float2(c, s); logi[nrot] = i; }  // QL: sigma=+s
        nrot++;
      }
      dd[l] = rlanef(dsn, l) - p;   // d[l] untouched by sweep writes
      ee[l] = g;
    }
    goto ql_top;
  } else {
    // ----- QR -----
qr_top:
    dsn = dd[row];
    esn = ee[row];
    {
      int mm;
      for (mm = l; mm > lend; --mm) {
        float eI = rlanef(esn, mm - 1);
        float tst = eI * eI;
        if (tst <= (EPS2F * fabsf(rlanef(dsn, mm))) * fabsf(rlanef(dsn, mm - 1)) + SAFMINF) break;
      }
      m = mm;
    }
    if (m > lend) ee[m - 1] = 0.f;
    {
      float p = rlanef(dsn, l);
      if (m == l) {
        dd[l] = p;
        l = l - 1;
        if (l >= lend) goto qr_top;
        goto blk_done;
      }
      if (m == l - 1) {
        float rt1, rt2, c2, s2;
        slaev2(rlanef(dsn, l - 1), rlanef(esn, l - 1), rlanef(dsn, l), &rt1, &rt2, &c2, &s2);
        if (lane == 0 && nrot < MAXLOG) { logcs[nrot] = make_float2(c2, -s2); logi[nrot] = l - 1; }
        nrot++;
        dd[l - 1] = rt1; dd[l] = rt2; ee[l - 1] = 0.f;
        l -= 2;
        if (l >= lend) goto qr_top;
        goto blk_done;
      }
      if (jtot == nmaxit) goto blk_done;
      jtot++;
      float g = (rlanef(dsn, l - 1) - p) / (2.f * rlanef(esn, l - 1));
      float r = slapy2(g, 1.f);
      g = rlanef(dsn, m) - p + rlanef(esn, l - 1) / (g + ssign(r, g));
      float s = 1.f, c = 1.f;
      p = 0.f;
      for (int i = m; i <= l - 1; ++i) {
        float eI = rlanef(esn, i);
        float f = s * eI;
        float bb = c * eI;
        slartg(g, f, &c, &s, &r);
        if (i != m) ee[i - 1] = r;
        g = rlanef(dsn, i) - p;
        r = (rlanef(dsn, i + 1) - g) * s + 2.f * c * bb;
        p = s * r;
        dd[i] = g + p;
        g = c * r - bb;
        if (lane == 0 && nrot < MAXLOG) { logcs[nrot] = make_float2(c, -s); logi[nrot] = i; }  // QR: sigma=-s
        nrot++;
      }
      dd[l] = rlanef(dsn, l) - p;
      ee[l - 1] = g;
    }
    goto qr_top;
  }
blk_done:
  goto outer;

done:;
  // -------- NEW sign-safe epilogue: kmax + fast replay + back-transform ----
  // top eigenvalue index (serial scan preserves LAPACK's tie-breaking)
  dsn = dd[row];
  int kmax = 0;
  float dmax = rlanef(dsn, 0);
  for (int j = 1; j < 16; ++j) {
    float dj = rlanef(dsn, j);
    if (dj > dmax) { dmax = dj; kmax = j; }
  }

  // pad the rotation log to a multiple of 64 with sentinel i=255: no lane
  // matches, so padded slots apply NO arithmetic to w (exact no-op).
  int cap = nrot < MAXLOG ? nrot : MAXLOG;
  int padded = (cap + 63) & ~63;
  for (int j = cap + lane; j < padded; j += 64) logi[j] = 255;

  // reverse replay: w = G_0(G_1(...(G_{n-1} e_kmax)))
  //   (G*w)[i] = c*w[i] + sg*w[i+1]; (G*w)[i+1] = -sg*w[i] + c*w[i+1]
  // Batches of 64, fully unrolled; (c,sg,i) are uniform-address LDS broadcast
  // loads (pipeline ahead of the w-chain); the w-chain is DPP+FMA+cndmask.
  float w = (lane == kmax) ? 1.f : 0.f;
  for (int base = padded - 64; base >= 0; base -= 64) {
#pragma unroll
    for (int k = 63; k >= 0; --k) {
      float2 cs = logcs[base + k];
      int i = logi[base + k];
      float wdn = dpp_shl1(w);   // w[lane+1]
      float wup = dpp_shr1(w);   // w[lane-1]
      float ca = cs.x * w + cs.y * wdn;     // candidate for lane == i
      float cb = -cs.y * wup + cs.x * w;    // candidate for lane == i+1
      w = (lane == i) ? ca : ((lane == i + 1) ? cb : w);
    }
  }

  float vreg = (lane < 16) ? w : 0.f;
  // back-transform: v := H(0) H(1) ... H(14) v  (apply H(14) first)
  for (int i = 14; i >= 0; --i) {
    float taui = ttl[lane][i];
    if (taui == 0.f) continue;
    float contrib;
    if (lane == i + 1) contrib = vreg;
    else if (lane >= i + 2 && lane < 16) contrib = A[lane][i] * vreg;
    else contrib = 0.f;
    float dot = wsum64(contrib);
    float td = taui * dot;
    if (lane == i + 1) vreg -= td;
    else if (lane >= i + 2 && lane < 16) vreg -= td * A[lane][i];
  }

  float act = 1.f / (1.f + expf(-(dmax / trace - bias[pid & 31])));
  if (lane == 0) out[pid] = act;
  if (lane < 16) out[512 + pid * 16 + lane] = vreg;
}

extern "C" void kernel_launch(void* const* d_in, const int* in_sizes, int n_in,
                              void* d_out, int out_size, void* d_ws, size_t ws_size,
                              hipStream_t stream) {
  const float* in   = (const float*)d_in[0];   // [16,14,14,544] fp32
  const float* W    = (const float*)d_in[1];   // [1,32,32,4,4] fp32
  const float* bias = (const float*)d_in[2];   // [32] fp32
  float* out = (float*)d_out;

  float* Mbuf = (float*)d_ws;            // 512*256 floats = 512 KB
  float* Gbuf = Mbuf + 512 * 256;        // 512*256 floats = 512 KB

  moments_kernel<<<512, 256, 0, stream>>>(in, Mbuf);
  gram_kernel<<<512, 256, 0, stream>>>(Mbuf, W, Gbuf);
  eig_kernel<<<512, 64, 0, stream>>>(Gbuf, bias, out);
}

// Round 4
// 237.310 us; speedup vs baseline: 1.0904x; 1.0404x over previous
//
#include <hip/hip_runtime.h>
#include <hip/hip_bf16.h>

// ConvCaps spectral routing.
//   activations[b,o] = sigmoid(lambda_max(G)/tr(G) - bias[o])
//   poses[b,o,:]     = top eigenvector of G, matching LAPACK ssyevd sign conventions.
// R14: replay tail v3 (R13 post-mortem: uniform-address LDS loads inside the
// unrolled rotation chain ran at partially-hidden ~120cy ds_read latency).
//   - per-lane REGISTER batching (one LDS read per 64 rotations: lane k holds
//     rotation base+k), wave-uniform v_readlane broadcasts off the w-chain;
//   - DPP row_shl/row_shr adjacent exchange on the chain (R13, kept);
//   - back-transform: wsum64 (6-deep LDS-pipe shfl chain ~210cy) replaced by
//     4-step DPP row_shr inclusive scan + readlane(15) broadcast (~40cy).
// All edits strictly after done: (sign-safe zone; R12/R13 both proved the
// frozen region's decision bits are unaffected by epilogue edits).
// Everything through done: BYTE-VERBATIM R10/R12/R13 frozen text.
// moments/gram BYTE-VERBATIM (G bits must not move).

#define NSPAT 196

__device__ __forceinline__ float wsum64(float x) {
  x += __shfl_xor(x, 32);
  x += __shfl_xor(x, 16);
  x += __shfl_xor(x, 8);
  x += __shfl_xor(x, 4);
  x += __shfl_xor(x, 2);
  x += __shfl_xor(x, 1);
  return x;
}

// wave-uniform lane read: v_readlane_b32 (SGPR result, no LDS traffic)
__device__ __forceinline__ float rlanef(float x, int i) {
  return __int_as_float(__builtin_amdgcn_readlane(__float_as_int(x), i));
}

// DPP adjacent exchanges within 16-lane rows (VALU latency, no LDS pipe).
// dpp_shl1: lane i reads lane i+1 (ROW_SHL:1 = 0x101)  [__shfl_down(x,1)]
// dpp_shr1: lane i reads lane i-1 (ROW_SHR:1 = 0x111)  [__shfl_up(x,1)]
// Row-edge lanes get 0 (bound_ctrl) — only consumed by lanes that never
// match the rotation index, so don't-care.
__device__ __forceinline__ float dpp_shl1(float x) {
  return __int_as_float(__builtin_amdgcn_update_dpp(0, __float_as_int(x), 0x101, 0xf, 0xf, true));
}
__device__ __forceinline__ float dpp_shr1(float x) {
  return __int_as_float(__builtin_amdgcn_update_dpp(0, __float_as_int(x), 0x111, 0xf, 0xf, true));
}

// 16-lane row reduction: DPP row_shr inclusive scan, then lane-15 broadcast.
// Input must be zero outside lanes 0..15 (epilogue-only; NOT used in the
// frozen region, which keeps wsum64 byte-verbatim).
#define DPPADD(x, ctrl) \
  ((x) + __int_as_float(__builtin_amdgcn_update_dpp(0, __float_as_int(x), (ctrl), 0xf, 0xf, true)))
__device__ __forceinline__ float rowsum16_bcast(float x) {
  x = DPPADD(x, 0x111);   // ROW_SHR:1
  x = DPPADD(x, 0x112);   // ROW_SHR:2
  x = DPPADD(x, 0x114);   // ROW_SHR:4
  x = DPPADD(x, 0x118);   // ROW_SHR:8  -> lane15 holds sum of lanes 0..15
  return rlanef(x, 15);
}

// ---------------- kernel A: per-(b,l) moment matrices -----------------------
__global__ __launch_bounds__(256) void moments_kernel(const float* __restrict__ in,
                                                      float* __restrict__ Mout) {
  int b = blockIdx.x >> 5;
  int l = blockIdx.x & 31;
  __shared__ float ps[NSPAT][16];
  __shared__ float as2[NSPAT];
  int t = threadIdx.x;
  const float4* in4 = (const float4*)in;
  for (int j = t; j < NSPAT * 4; j += 256) {
    int s = j >> 2, q = j & 3;
    ((float4*)ps)[j] = in4[(size_t)(b * NSPAT + s) * 136 + l * 4 + q];
  }
  for (int s = t; s < NSPAT; s += 256) {
    float a = in[((size_t)(b * NSPAT + s)) * 544 + 512 + l];
    as2[s] = a * a;
  }
  __syncthreads();
  int p = t >> 4, q = t & 15;
  float acc = 0.f;
  for (int s = 0; s < NSPAT; ++s) {
    // FROZEN TEXT: symmetric-exact accumulation order feeds the eig path bits
    acc += as2[s] * (ps[s][p] * ps[s][q]);
  }
  Mout[(size_t)blockIdx.x * 256 + t] = acc;
}

// ---------------- kernel B: contract moments with weights -> gram ----------
__global__ __launch_bounds__(256) void gram_kernel(const float* __restrict__ Min,
                                                   const float* __restrict__ W,
                                                   float* __restrict__ Gout) {
  int b = blockIdx.x >> 5;
  int o = blockIdx.x & 31;
  int t = threadIdx.x;
  __shared__ float Ms[32][256];
  __shared__ float Ws[32][16];
  const float4* Min4 = (const float4*)Min;
  const float4* W4 = (const float4*)W;
  for (int j = t; j < 2048; j += 256)
    ((float4*)Ms)[j] = Min4[(size_t)b * 2048 + j];
  for (int j = t; j < 128; j += 256) {
    int l = j >> 2, q = j & 3;
    ((float4*)Ws)[j] = W4[(size_t)(l * 32 + o) * 4 + q];
  }
  __syncthreads();
  int p = t >> 4, q = t & 15;
  int i1 = p >> 2, k1 = p & 3, i2 = q >> 2, k2 = q & 3;
  float acc = 0.f;
  for (int l = 0; l < 32; ++l) {
    float sub = 0.f;
    for (int j2 = 0; j2 < 4; ++j2) {
      float inner = 0.f;
      for (int j = 0; j < 4; ++j)
        inner += Ws[l][j * 4 + k1] * Ms[l][(i1 * 4 + j) * 16 + (i2 * 4 + j2)];
      sub += Ws[l][j2 * 4 + k2] * inner;
    }
    acc += sub;
  }
  Gout[(size_t)blockIdx.x * 256 + t] = acc;
}

// ---------------- LAPACK fp32 helpers (sign-faithful, FROZEN TEXT) ---------
#define EPSF    5.9604645e-08f   /* slamch('E') = 2^-24 */
#define EPS2F   (EPSF * EPSF)
#define SAFMINF 1.1754944e-38f   /* slamch('S') */

__device__ __forceinline__ float ssign(float a, float b) {
  return (b >= 0.f) ? fabsf(a) : -fabsf(a);
}

__device__ __forceinline__ float slapy2(float x, float y) {
  float xa = fabsf(x), ya = fabsf(y);
  float w = fmaxf(xa, ya), z = fminf(xa, ya);
  if (z == 0.f) return w;
  float t = z / w;
  return w * sqrtf(1.f + t * t);
}

// LAPACK >= 3.10 slartg convention (c >= 0, r carries sign of f)
__device__ __forceinline__ void slartg(float f, float g, float* c, float* s, float* r) {
  if (g == 0.f) {
    *c = 1.f; *s = 0.f; *r = f;
  } else if (f == 0.f) {
    *c = 0.f; *s = (g >= 0.f) ? 1.f : -1.f; *r = fabsf(g);
  } else {
    float d = sqrtf(f * f + g * g);
    *c = fabsf(f) / d;
    float rr = (f >= 0.f) ? d : -d;
    *s = g / rr;
    *r = rr;
  }
}

__device__ __forceinline__ void slaev2(float a, float b, float c,
                                       float* rt1, float* rt2, float* cs1, float* sn1) {
  float sm = a + c;
  float df = a - c;
  float adf = fabsf(df);
  float tb = b + b;
  float ab = fabsf(tb);
  float acmx, acmn;
  if (fabsf(a) > fabsf(c)) { acmx = a; acmn = c; } else { acmx = c; acmn = a; }
  float rt;
  if (adf > ab)      { float t = ab / adf; rt = adf * sqrtf(1.f + t * t); }
  else if (adf < ab) { float t = adf / ab; rt = ab * sqrtf(1.f + t * t); }
  else               { rt = ab * sqrtf(2.f); }
  int sgn1;
  if (sm < 0.f) {
    *rt1 = 0.5f * (sm - rt); sgn1 = -1;
    *rt2 = (acmx / *rt1) * acmn - (b / *rt1) * b;
  } else if (sm > 0.f) {
    *rt1 = 0.5f * (sm + rt); sgn1 = 1;
    *rt2 = (acmx / *rt1) * acmn - (b / *rt1) * b;
  } else {
    *rt1 = 0.5f * rt; *rt2 = -0.5f * rt; sgn1 = 1;
  }
  float cs; int sgn2;
  if (df >= 0.f) { cs = df + rt; sgn2 = 1; }
  else           { cs = df - rt; sgn2 = -1; }
  float acs = fabsf(cs);
  float c1, s1;
  if (acs > ab) {
    float ct = -tb / cs;
    s1 = 1.f / sqrtf(1.f + ct * ct);
    c1 = ct * s1;
  } else {
    if (ab == 0.f) { c1 = 1.f; s1 = 0.f; }
    else {
      float tn = -cs / tb;
      c1 = 1.f / sqrtf(1.f + tn * tn);
      s1 = tn * c1;
    }
  }
  if (sgn1 == sgn2) { float tn = c1; c1 = -s1; s1 = tn; }
  *cs1 = c1; *sn1 = s1;
}

#define MAXLOG 1024

// ---------------- kernel C: one wave per 16x16 eig problem -----------------
// Entry through `done:` is BYTE-VERBATIM the frozen recurrence (in-loop LDS
// log stores untouched). Epilogue after done: is the new sign-safe fast
// replay (register-batched readlane + DPP) + DPP back-transform.
__global__ __launch_bounds__(64) void eig_kernel(const float* __restrict__ G,
                                                 const float* __restrict__ bias,
                                                 float* __restrict__ out) {
  const int pid = blockIdx.x;   // b*32 + o
  const int lane = threadIdx.x;
  const int row = lane & 15;
  __shared__ float A[16][17];      // working matrix / householder vectors
  __shared__ float ddl[64][17];    // per-lane replicated d
  __shared__ float eel[64][17];    // per-lane replicated e
  __shared__ float ttl[64][17];    // per-lane replicated tau
  __shared__ float2 logcs[MAXLOG]; // rotation log: (c, sigma)
  __shared__ int    logi[MAXLOG];  // rotation log: column index i

  // load + symmetrize (use lower triangle)
  for (int k = 0; k < 4; ++k) {
    int t = lane + 64 * k;
    int r = t >> 4, c = t & 15;
    int rr = r >= c ? r : c;
    int cc = r >= c ? c : r;
    A[r][c] = G[(size_t)pid * 256 + rr * 16 + cc];
  }
  float trc = (lane < 16) ? G[(size_t)pid * 256 + lane * 17] : 0.f;
  float trace = wsum64(trc);
  __syncthreads();

  // ---- ssytd2 (lower) ----
  for (int i = 0; i < 15; ++i) {
    float acol = (lane < 16) ? A[lane][i] : 0.f;
    float alpha = __shfl(acol, i + 1);
    float x = (lane >= i + 2 && lane < 16) ? acol : 0.f;
    float xns = wsum64(x * x);
    if (xns == 0.f) {
      eel[lane][i] = alpha;
      ttl[lane][i] = 0.f;
      continue;
    }
    float beta = (alpha >= 0.f ? -1.f : 1.f) * sqrtf(alpha * alpha + xns);
    float taui = (beta - alpha) / beta;
    float scal = 1.f / (alpha - beta);
    float vreg = 0.f;
    if (lane == i + 1) vreg = 1.f;
    else if (lane >= i + 2 && lane < 16) {
      vreg = acol * scal;
      A[lane][i] = vreg;   // persist householder vector (lane-local write)
    }
    eel[lane][i] = beta;
    ttl[lane][i] = taui;
    float wr = 0.f;
    for (int cI = i + 1; cI < 16; ++cI) {
      float vc = __shfl(vreg, cI);
      if (lane >= i + 1 && lane < 16) wr += A[lane][cI] * vc;
    }
    wr *= taui;
    float dot = wsum64((lane >= i + 1 && lane < 16) ? wr * vreg : 0.f);
    float alpha2 = -0.5f * taui * dot;
    wr += alpha2 * vreg;
    for (int cI = i + 1; cI < 16; ++cI) {
      float wc = __shfl(wr, cI);
      float vc = __shfl(vreg, cI);
      if (lane >= i + 1 && lane < 16) A[lane][cI] -= vreg * wc + wr * vc;
    }
  }

  // gather d into per-lane replicated arrays
  float di = (lane < 16) ? A[lane][lane] : 0.f;
  for (int j = 0; j < 16; ++j) ddl[lane][j] = __shfl(di, j);

  float* dd = ddl[lane];
  float* ee = eel[lane];
  ee[15] = 0.f;   // pad slot for snapshots

  // ---- ssteqr('I') ----
  int m, l, lsv, lend, lendsv;
  int jtot = 0;
  const int nmaxit = 16 * 30;
  int l1 = 0;
  int nrot = 0;
  float dsn, esn;   // snapshots: lane j holds d[j] / e[j]

outer:
  if (l1 > 15) goto done;
  if (l1 > 0) ee[l1 - 1] = 0.f;
  dsn = dd[row];   // outer-top snapshot (after the e zeroing above)
  esn = ee[row];
  {
    int mm;
    for (mm = l1; mm < 15; ++mm) {
      float eI = rlanef(esn, mm);
      float tst = fabsf(eI);
      if (tst == 0.f) break;
      if (tst <= (sqrtf(fabsf(rlanef(dsn, mm))) * sqrtf(fabsf(rlanef(dsn, mm + 1)))) * EPSF) {
        ee[mm] = 0.f;
        break;
      }
    }
    m = mm;
  }
  l = l1; lsv = l; lend = m; lendsv = lend;
  l1 = m + 1;
  if (lend == l) goto outer;
  {
    // anorm over [l, lend] (the scan's ee[m]=0 write is outside this range)
    float an = 0.f;
    for (int k2 = l; k2 <= lend; ++k2) an = fmaxf(an, fabsf(rlanef(dsn, k2)));
    for (int k2 = l; k2 < lend; ++k2) an = fmaxf(an, fabsf(rlanef(esn, k2)));
    if (an == 0.f) goto outer;
  }
  if (fabsf(rlanef(dsn, lend)) < fabsf(rlanef(dsn, l))) { lend = lsv; l = lendsv; }

  if (lend > l) {
    // ----- QL -----
ql_top:
    dsn = dd[row];   // refresh snapshot (pre-sweep values)
    esn = ee[row];
    {
      int mm;
      for (mm = l; mm < lend; ++mm) {
        float eI = rlanef(esn, mm);
        float tst = eI * eI;
        if (tst <= (EPS2F * fabsf(rlanef(dsn, mm))) * fabsf(rlanef(dsn, mm + 1)) + SAFMINF) break;
      }
      m = mm;
    }
    if (m < lend) ee[m] = 0.f;   // pre-snapshot reads below all use idx < m
    {
      float p = rlanef(dsn, l);
      if (m == l) {
        dd[l] = p;
        l = l + 1;
        if (l <= lend) goto ql_top;
        goto blk_done;
      }
      if (m == l + 1) {
        float rt1, rt2, c2, s2;
        slaev2(rlanef(dsn, l), rlanef(esn, l), rlanef(dsn, l + 1), &rt1, &rt2, &c2, &s2);
        if (lane == 0 && nrot < MAXLOG) { logcs[nrot] = make_float2(c2, -s2); logi[nrot] = l; }
        nrot++;
        dd[l] = rt1; dd[l + 1] = rt2; ee[l] = 0.f;
        l += 2;
        if (l <= lend) goto ql_top;
        goto blk_done;
      }
      if (jtot == nmaxit) goto blk_done;
      jtot++;
      float g = (rlanef(dsn, l + 1) - p) / (2.f * rlanef(esn, l));
      float r = slapy2(g, 1.f);
      g = rlanef(dsn, m) - p + rlanef(esn, l) / (g + ssign(r, g));
      float s = 1.f, c = 1.f;
      p = 0.f;
      for (int i = m - 1; i >= l; --i) {
        float eI = rlanef(esn, i);
        float f = s * eI;
        float bb = c * eI;
        slartg(g, f, &c, &s, &r);
        if (i != m - 1) ee[i + 1] = r;
        g = rlanef(dsn, i + 1) - p;
        r = (rlanef(dsn, i) - g) * s + 2.f * c * bb;
        p = s * r;
        dd[i + 1] = g + p;
        g = c * r - bb;
        if (lane == 0 && nrot < MAXLOG) { logcs[nrot] = make_float2(c, s); logi[nrot] = i; }  // QL: sigma=+s
        nrot++;
      }
      dd[l] = rlanef(dsn, l) - p;   // d[l] untouched by sweep writes
      ee[l] = g;
    }
    goto ql_top;
  } else {
    // ----- QR -----
qr_top:
    dsn = dd[row];
    esn = ee[row];
    {
      int mm;
      for (mm = l; mm > lend; --mm) {
        float eI = rlanef(esn, mm - 1);
        float tst = eI * eI;
        if (tst <= (EPS2F * fabsf(rlanef(dsn, mm))) * fabsf(rlanef(dsn, mm - 1)) + SAFMINF) break;
      }
      m = mm;
    }
    if (m > lend) ee[m - 1] = 0.f;
    {
      float p = rlanef(dsn, l);
      if (m == l) {
        dd[l] = p;
        l = l - 1;
        if (l >= lend) goto qr_top;
        goto blk_done;
      }
      if (m == l - 1) {
        float rt1, rt2, c2, s2;
        slaev2(rlanef(dsn, l - 1), rlanef(esn, l - 1), rlanef(dsn, l), &rt1, &rt2, &c2, &s2);
        if (lane == 0 && nrot < MAXLOG) { logcs[nrot] = make_float2(c2, -s2); logi[nrot] = l - 1; }
        nrot++;
        dd[l - 1] = rt1; dd[l] = rt2; ee[l - 1] = 0.f;
        l -= 2;
        if (l >= lend) goto qr_top;
        goto blk_done;
      }
      if (jtot == nmaxit) goto blk_done;
      jtot++;
      float g = (rlanef(dsn, l - 1) - p) / (2.f * rlanef(esn, l - 1));
      float r = slapy2(g, 1.f);
      g = rlanef(dsn, m) - p + rlanef(esn, l - 1) / (g + ssign(r, g));
      float s = 1.f, c = 1.f;
      p = 0.f;
      for (int i = m; i <= l - 1; ++i) {
        float eI = rlanef(esn, i);
        float f = s * eI;
        float bb = c * eI;
        slartg(g, f, &c, &s, &r);
        if (i != m) ee[i - 1] = r;
        g = rlanef(dsn, i) - p;
        r = (rlanef(dsn, i + 1) - g) * s + 2.f * c * bb;
        p = s * r;
        dd[i] = g + p;
        g = c * r - bb;
        if (lane == 0 && nrot < MAXLOG) { logcs[nrot] = make_float2(c, -s); logi[nrot] = i; }  // QR: sigma=-s
        nrot++;
      }
      dd[l] = rlanef(dsn, l) - p;
      ee[l - 1] = g;
    }
    goto qr_top;
  }
blk_done:
  goto outer;

done:;
  // -------- sign-safe epilogue: kmax + fast replay + back-transform --------
  // top eigenvalue index (serial scan preserves LAPACK's tie-breaking)
  dsn = dd[row];
  int kmax = 0;
  float dmax = rlanef(dsn, 0);
  for (int j = 1; j < 16; ++j) {
    float dj = rlanef(dsn, j);
    if (dj > dmax) { dmax = dj; kmax = j; }
  }

  // pad the rotation log to a multiple of 64 with sentinel i=255: no lane
  // matches, so padded slots apply NO arithmetic to w (exact no-op).
  int cap = nrot < MAXLOG ? nrot : MAXLOG;
  int padded = (cap + 63) & ~63;
  for (int j = cap + lane; j < padded; j += 64) {
    logi[j] = 255;
    logcs[j] = make_float2(1.f, 0.f);
  }

  // reverse replay: w = G_0(G_1(...(G_{n-1} e_kmax)))
  //   (G*w)[i] = c*w[i] + sg*w[i+1]; (G*w)[i+1] = -sg*w[i] + c*w[i+1]
  // Register-batched: ONE LDS read per 64 rotations (lane k holds rotation
  // base+k), then wave-uniform v_readlane broadcasts (off the w-chain).
  // The w-chain itself is DPP + FMA + cndmask — pure VALU latency, no LDS.
  float w = (lane == kmax) ? 1.f : 0.f;
  for (int base = padded - 64; base >= 0; base -= 64) {
    float2 bcs = logcs[base + lane];
    int bii = logi[base + lane];
#pragma unroll
    for (int k = 63; k >= 0; --k) {
      float c = rlanef(bcs.x, k);
      float sg = rlanef(bcs.y, k);
      int i = __builtin_amdgcn_readlane(bii, k);
      float wdn = dpp_shl1(w);   // w[lane+1]
      float wup = dpp_shr1(w);   // w[lane-1]
      float ca = c * w + sg * wdn;     // candidate for lane == i
      float cb = -sg * wup + c * w;    // candidate for lane == i+1
      w = (lane == i) ? ca : ((lane == i + 1) ? cb : w);
    }
  }

  float vreg = (lane < 16) ? w : 0.f;
  // back-transform: v := H(0) H(1) ... H(14) v  (apply H(14) first)
  // DPP row-scan reduction (~40cy) replaces the 6-deep shfl_xor chain.
  for (int i = 14; i >= 0; --i) {
    float taui = ttl[lane][i];
    if (taui == 0.f) continue;
    float contrib;
    if (lane == i + 1) contrib = vreg;
    else if (lane >= i + 2 && lane < 16) contrib = A[lane][i] * vreg;
    else contrib = 0.f;
    float dot = rowsum16_bcast(contrib);
    float td = taui * dot;
    if (lane == i + 1) vreg -= td;
    else if (lane >= i + 2 && lane < 16) vreg -= td * A[lane][i];
  }

  float act = 1.f / (1.f + expf(-(dmax / trace - bias[pid & 31])));
  if (lane == 0) out[pid] = act;
  if (lane < 16) out[512 + pid * 16 + lane] = vreg;
}

extern "C" void kernel_launch(void* const* d_in, const int* in_sizes, int n_in,
                              void* d_out, int out_size, void* d_ws, size_t ws_size,
                              hipStream_t stream) {
  const float* in   = (const float*)d_in[0];   // [16,14,14,544] fp32
  const float* W    = (const float*)d_in[1];   // [1,32,32,4,4] fp32
  const float* bias = (const float*)d_in[2];   // [32] fp32
  float* out = (float*)d_out;

  float* Mbuf = (float*)d_ws;            // 512*256 floats = 512 KB
  float* Gbuf = Mbuf + 512 * 256;        // 512*256 floats = 512 KB

  moments_kernel<<<512, 256, 0, stream>>>(in, Mbuf);
  gram_kernel<<<512, 256, 0, stream>>>(Mbuf, W, Gbuf);
  eig_kernel<<<512, 64, 0, stream>>>(Gbuf, bias, out);
}

// Round 6
// 235.647 us; speedup vs baseline: 1.0981x; 1.0071x over previous
//
#include <hip/hip_runtime.h>
#include <hip/hip_bf16.h>

// ConvCaps spectral routing.
//   activations[b,o] = sigmoid(lambda_max(G)/tr(G) - bias[o])
//   poses[b,o,:]     = top eigenvector of G, matching LAPACK ssyevd sign conventions.
// R15-resubmit (R5 bench was GPUAcquisitionTimeout — kernel never ran).
// R15: tail v4 (R14 post-mortem: replay now VALU-bound; remaining tail LDS
// latency is the back-transform's 15 serial dependent ds_reads of tau/A).
//   - preload tau column (ttl[lane][0..14]) and householder column
//     (A[lane][0..14], lane<16) into REGISTERS with statically-indexed
//     unrolled loads -> compiler batch-issues ~30 ds_reads + ONE lgkmcnt wait
//     (~200cy) instead of 15 serial dependent pairs (~3600cy);
//   - back-transform fully unrolled on registers (DPP rowsum kept from R14);
//   - replay: software-pipelined next-batch prefetch (LDS read of batch n-1
//     issues before the 64-rotation unrolled body of batch n).
// All edits strictly after done: (sign-safe zone; R12/R13/R14 proved the
// frozen region's decision bits are unaffected by epilogue edits).
// Everything through done: BYTE-VERBATIM frozen text.
// moments/gram BYTE-VERBATIM (G bits must not move).

#define NSPAT 196

__device__ __forceinline__ float wsum64(float x) {
  x += __shfl_xor(x, 32);
  x += __shfl_xor(x, 16);
  x += __shfl_xor(x, 8);
  x += __shfl_xor(x, 4);
  x += __shfl_xor(x, 2);
  x += __shfl_xor(x, 1);
  return x;
}

// wave-uniform lane read: v_readlane_b32 (SGPR result, no LDS traffic)
__device__ __forceinline__ float rlanef(float x, int i) {
  return __int_as_float(__builtin_amdgcn_readlane(__float_as_int(x), i));
}

// DPP adjacent exchanges within 16-lane rows (VALU latency, no LDS pipe).
// dpp_shl1: lane i reads lane i+1 (ROW_SHL:1 = 0x101)  [__shfl_down(x,1)]
// dpp_shr1: lane i reads lane i-1 (ROW_SHR:1 = 0x111)  [__shfl_up(x,1)]
// Row-edge lanes get 0 (bound_ctrl) — only consumed by lanes that never
// match the rotation index, so don't-care.
__device__ __forceinline__ float dpp_shl1(float x) {
  return __int_as_float(__builtin_amdgcn_update_dpp(0, __float_as_int(x), 0x101, 0xf, 0xf, true));
}
__device__ __forceinline__ float dpp_shr1(float x) {
  return __int_as_float(__builtin_amdgcn_update_dpp(0, __float_as_int(x), 0x111, 0xf, 0xf, true));
}

// 16-lane row reduction: DPP row_shr inclusive scan, then lane-15 broadcast.
// Input must be zero outside lanes 0..15 (epilogue-only; NOT used in the
// frozen region, which keeps wsum64 byte-verbatim).
#define DPPADD(x, ctrl) \
  ((x) + __int_as_float(__builtin_amdgcn_update_dpp(0, __float_as_int(x), (ctrl), 0xf, 0xf, true)))
__device__ __forceinline__ float rowsum16_bcast(float x) {
  x = DPPADD(x, 0x111);   // ROW_SHR:1
  x = DPPADD(x, 0x112);   // ROW_SHR:2
  x = DPPADD(x, 0x114);   // ROW_SHR:4
  x = DPPADD(x, 0x118);   // ROW_SHR:8  -> lane15 holds sum of lanes 0..15
  return rlanef(x, 15);
}

// ---------------- kernel A: per-(b,l) moment matrices -----------------------
__global__ __launch_bounds__(256) void moments_kernel(const float* __restrict__ in,
                                                      float* __restrict__ Mout) {
  int b = blockIdx.x >> 5;
  int l = blockIdx.x & 31;
  __shared__ float ps[NSPAT][16];
  __shared__ float as2[NSPAT];
  int t = threadIdx.x;
  const float4* in4 = (const float4*)in;
  for (int j = t; j < NSPAT * 4; j += 256) {
    int s = j >> 2, q = j & 3;
    ((float4*)ps)[j] = in4[(size_t)(b * NSPAT + s) * 136 + l * 4 + q];
  }
  for (int s = t; s < NSPAT; s += 256) {
    float a = in[((size_t)(b * NSPAT + s)) * 544 + 512 + l];
    as2[s] = a * a;
  }
  __syncthreads();
  int p = t >> 4, q = t & 15;
  float acc = 0.f;
  for (int s = 0; s < NSPAT; ++s) {
    // FROZEN TEXT: symmetric-exact accumulation order feeds the eig path bits
    acc += as2[s] * (ps[s][p] * ps[s][q]);
  }
  Mout[(size_t)blockIdx.x * 256 + t] = acc;
}

// ---------------- kernel B: contract moments with weights -> gram ----------
__global__ __launch_bounds__(256) void gram_kernel(const float* __restrict__ Min,
                                                   const float* __restrict__ W,
                                                   float* __restrict__ Gout) {
  int b = blockIdx.x >> 5;
  int o = blockIdx.x & 31;
  int t = threadIdx.x;
  __shared__ float Ms[32][256];
  __shared__ float Ws[32][16];
  const float4* Min4 = (const float4*)Min;
  const float4* W4 = (const float4*)W;
  for (int j = t; j < 2048; j += 256)
    ((float4*)Ms)[j] = Min4[(size_t)b * 2048 + j];
  for (int j = t; j < 128; j += 256) {
    int l = j >> 2, q = j & 3;
    ((float4*)Ws)[j] = W4[(size_t)(l * 32 + o) * 4 + q];
  }
  __syncthreads();
  int p = t >> 4, q = t & 15;
  int i1 = p >> 2, k1 = p & 3, i2 = q >> 2, k2 = q & 3;
  float acc = 0.f;
  for (int l = 0; l < 32; ++l) {
    float sub = 0.f;
    for (int j2 = 0; j2 < 4; ++j2) {
      float inner = 0.f;
      for (int j = 0; j < 4; ++j)
        inner += Ws[l][j * 4 + k1] * Ms[l][(i1 * 4 + j) * 16 + (i2 * 4 + j2)];
      sub += Ws[l][j2 * 4 + k2] * inner;
    }
    acc += sub;
  }
  Gout[(size_t)blockIdx.x * 256 + t] = acc;
}

// ---------------- LAPACK fp32 helpers (sign-faithful, FROZEN TEXT) ---------
#define EPSF    5.9604645e-08f   /* slamch('E') = 2^-24 */
#define EPS2F   (EPSF * EPSF)
#define SAFMINF 1.1754944e-38f   /* slamch('S') */

__device__ __forceinline__ float ssign(float a, float b) {
  return (b >= 0.f) ? fabsf(a) : -fabsf(a);
}

__device__ __forceinline__ float slapy2(float x, float y) {
  float xa = fabsf(x), ya = fabsf(y);
  float w = fmaxf(xa, ya), z = fminf(xa, ya);
  if (z == 0.f) return w;
  float t = z / w;
  return w * sqrtf(1.f + t * t);
}

// LAPACK >= 3.10 slartg convention (c >= 0, r carries sign of f)
__device__ __forceinline__ void slartg(float f, float g, float* c, float* s, float* r) {
  if (g == 0.f) {
    *c = 1.f; *s = 0.f; *r = f;
  } else if (f == 0.f) {
    *c = 0.f; *s = (g >= 0.f) ? 1.f : -1.f; *r = fabsf(g);
  } else {
    float d = sqrtf(f * f + g * g);
    *c = fabsf(f) / d;
    float rr = (f >= 0.f) ? d : -d;
    *s = g / rr;
    *r = rr;
  }
}

__device__ __forceinline__ void slaev2(float a, float b, float c,
                                       float* rt1, float* rt2, float* cs1, float* sn1) {
  float sm = a + c;
  float df = a - c;
  float adf = fabsf(df);
  float tb = b + b;
  float ab = fabsf(tb);
  float acmx, acmn;
  if (fabsf(a) > fabsf(c)) { acmx = a; acmn = c; } else { acmx = c; acmn = a; }
  float rt;
  if (adf > ab)      { float t = ab / adf; rt = adf * sqrtf(1.f + t * t); }
  else if (adf < ab) { float t = adf / ab; rt = ab * sqrtf(1.f + t * t); }
  else               { rt = ab * sqrtf(2.f); }
  int sgn1;
  if (sm < 0.f) {
    *rt1 = 0.5f * (sm - rt); sgn1 = -1;
    *rt2 = (acmx / *rt1) * acmn - (b / *rt1) * b;
  } else if (sm > 0.f) {
    *rt1 = 0.5f * (sm + rt); sgn1 = 1;
    *rt2 = (acmx / *rt1) * acmn - (b / *rt1) * b;
  } else {
    *rt1 = 0.5f * rt; *rt2 = -0.5f * rt; sgn1 = 1;
  }
  float cs; int sgn2;
  if (df >= 0.f) { cs = df + rt; sgn2 = 1; }
  else           { cs = df - rt; sgn2 = -1; }
  float acs = fabsf(cs);
  float c1, s1;
  if (acs > ab) {
    float ct = -tb / cs;
    s1 = 1.f / sqrtf(1.f + ct * ct);
    c1 = ct * s1;
  } else {
    if (ab == 0.f) { c1 = 1.f; s1 = 0.f; }
    else {
      float tn = -cs / tb;
      c1 = 1.f / sqrtf(1.f + tn * tn);
      s1 = tn * c1;
    }
  }
  if (sgn1 == sgn2) { float tn = c1; c1 = -s1; s1 = tn; }
  *cs1 = c1; *sn1 = s1;
}

#define MAXLOG 1024

// ---------------- kernel C: one wave per 16x16 eig problem -----------------
// Entry through `done:` is BYTE-VERBATIM the frozen recurrence (in-loop LDS
// log stores untouched). Epilogue after done: is the sign-safe fast tail v4.
__global__ __launch_bounds__(64) void eig_kernel(const float* __restrict__ G,
                                                 const float* __restrict__ bias,
                                                 float* __restrict__ out) {
  const int pid = blockIdx.x;   // b*32 + o
  const int lane = threadIdx.x;
  const int row = lane & 15;
  __shared__ float A[16][17];      // working matrix / householder vectors
  __shared__ float ddl[64][17];    // per-lane replicated d
  __shared__ float eel[64][17];    // per-lane replicated e
  __shared__ float ttl[64][17];    // per-lane replicated tau
  __shared__ float2 logcs[MAXLOG]; // rotation log: (c, sigma)
  __shared__ int    logi[MAXLOG];  // rotation log: column index i

  // load + symmetrize (use lower triangle)
  for (int k = 0; k < 4; ++k) {
    int t = lane + 64 * k;
    int r = t >> 4, c = t & 15;
    int rr = r >= c ? r : c;
    int cc = r >= c ? c : r;
    A[r][c] = G[(size_t)pid * 256 + rr * 16 + cc];
  }
  float trc = (lane < 16) ? G[(size_t)pid * 256 + lane * 17] : 0.f;
  float trace = wsum64(trc);
  __syncthreads();

  // ---- ssytd2 (lower) ----
  for (int i = 0; i < 15; ++i) {
    float acol = (lane < 16) ? A[lane][i] : 0.f;
    float alpha = __shfl(acol, i + 1);
    float x = (lane >= i + 2 && lane < 16) ? acol : 0.f;
    float xns = wsum64(x * x);
    if (xns == 0.f) {
      eel[lane][i] = alpha;
      ttl[lane][i] = 0.f;
      continue;
    }
    float beta = (alpha >= 0.f ? -1.f : 1.f) * sqrtf(alpha * alpha + xns);
    float taui = (beta - alpha) / beta;
    float scal = 1.f / (alpha - beta);
    float vreg = 0.f;
    if (lane == i + 1) vreg = 1.f;
    else if (lane >= i + 2 && lane < 16) {
      vreg = acol * scal;
      A[lane][i] = vreg;   // persist householder vector (lane-local write)
    }
    eel[lane][i] = beta;
    ttl[lane][i] = taui;
    float wr = 0.f;
    for (int cI = i + 1; cI < 16; ++cI) {
      float vc = __shfl(vreg, cI);
      if (lane >= i + 1 && lane < 16) wr += A[lane][cI] * vc;
    }
    wr *= taui;
    float dot = wsum64((lane >= i + 1 && lane < 16) ? wr * vreg : 0.f);
    float alpha2 = -0.5f * taui * dot;
    wr += alpha2 * vreg;
    for (int cI = i + 1; cI < 16; ++cI) {
      float wc = __shfl(wr, cI);
      float vc = __shfl(vreg, cI);
      if (lane >= i + 1 && lane < 16) A[lane][cI] -= vreg * wc + wr * vc;
    }
  }

  // gather d into per-lane replicated arrays
  float di = (lane < 16) ? A[lane][lane] : 0.f;
  for (int j = 0; j < 16; ++j) ddl[lane][j] = __shfl(di, j);

  float* dd = ddl[lane];
  float* ee = eel[lane];
  ee[15] = 0.f;   // pad slot for snapshots

  // ---- ssteqr('I') ----
  int m, l, lsv, lend, lendsv;
  int jtot = 0;
  const int nmaxit = 16 * 30;
  int l1 = 0;
  int nrot = 0;
  float dsn, esn;   // snapshots: lane j holds d[j] / e[j]

outer:
  if (l1 > 15) goto done;
  if (l1 > 0) ee[l1 - 1] = 0.f;
  dsn = dd[row];   // outer-top snapshot (after the e zeroing above)
  esn = ee[row];
  {
    int mm;
    for (mm = l1; mm < 15; ++mm) {
      float eI = rlanef(esn, mm);
      float tst = fabsf(eI);
      if (tst == 0.f) break;
      if (tst <= (sqrtf(fabsf(rlanef(dsn, mm))) * sqrtf(fabsf(rlanef(dsn, mm + 1)))) * EPSF) {
        ee[mm] = 0.f;
        break;
      }
    }
    m = mm;
  }
  l = l1; lsv = l; lend = m; lendsv = lend;
  l1 = m + 1;
  if (lend == l) goto outer;
  {
    // anorm over [l, lend] (the scan's ee[m]=0 write is outside this range)
    float an = 0.f;
    for (int k2 = l; k2 <= lend; ++k2) an = fmaxf(an, fabsf(rlanef(dsn, k2)));
    for (int k2 = l; k2 < lend; ++k2) an = fmaxf(an, fabsf(rlanef(esn, k2)));
    if (an == 0.f) goto outer;
  }
  if (fabsf(rlanef(dsn, lend)) < fabsf(rlanef(dsn, l))) { lend = lsv; l = lendsv; }

  if (lend > l) {
    // ----- QL -----
ql_top:
    dsn = dd[row];   // refresh snapshot (pre-sweep values)
    esn = ee[row];
    {
      int mm;
      for (mm = l; mm < lend; ++mm) {
        float eI = rlanef(esn, mm);
        float tst = eI * eI;
        if (tst <= (EPS2F * fabsf(rlanef(dsn, mm))) * fabsf(rlanef(dsn, mm + 1)) + SAFMINF) break;
      }
      m = mm;
    }
    if (m < lend) ee[m] = 0.f;   // pre-snapshot reads below all use idx < m
    {
      float p = rlanef(dsn, l);
      if (m == l) {
        dd[l] = p;
        l = l + 1;
        if (l <= lend) goto ql_top;
        goto blk_done;
      }
      if (m == l + 1) {
        float rt1, rt2, c2, s2;
        slaev2(rlanef(dsn, l), rlanef(esn, l), rlanef(dsn, l + 1), &rt1, &rt2, &c2, &s2);
        if (lane == 0 && nrot < MAXLOG) { logcs[nrot] = make_float2(c2, -s2); logi[nrot] = l; }
        nrot++;
        dd[l] = rt1; dd[l + 1] = rt2; ee[l] = 0.f;
        l += 2;
        if (l <= lend) goto ql_top;
        goto blk_done;
      }
      if (jtot == nmaxit) goto blk_done;
      jtot++;
      float g = (rlanef(dsn, l + 1) - p) / (2.f * rlanef(esn, l));
      float r = slapy2(g, 1.f);
      g = rlanef(dsn, m) - p + rlanef(esn, l) / (g + ssign(r, g));
      float s = 1.f, c = 1.f;
      p = 0.f;
      for (int i = m - 1; i >= l; --i) {
        float eI = rlanef(esn, i);
        float f = s * eI;
        float bb = c * eI;
        slartg(g, f, &c, &s, &r);
        if (i != m - 1) ee[i + 1] = r;
        g = rlanef(dsn, i + 1) - p;
        r = (rlanef(dsn, i) - g) * s + 2.f * c * bb;
        p = s * r;
        dd[i + 1] = g + p;
        g = c * r - bb;
        if (lane == 0 && nrot < MAXLOG) { logcs[nrot] = make_float2(c, s); logi[nrot] = i; }  // QL: sigma=+s
        nrot++;
      }
      dd[l] = rlanef(dsn, l) - p;   // d[l] untouched by sweep writes
      ee[l] = g;
    }
    goto ql_top;
  } else {
    // ----- QR -----
qr_top:
    dsn = dd[row];
    esn = ee[row];
    {
      int mm;
      for (mm = l; mm > lend; --mm) {
        float eI = rlanef(esn, mm - 1);
        float tst = eI * eI;
        if (tst <= (EPS2F * fabsf(rlanef(dsn, mm))) * fabsf(rlanef(dsn, mm - 1)) + SAFMINF) break;
      }
      m = mm;
    }
    if (m > lend) ee[m - 1] = 0.f;
    {
      float p = rlanef(dsn, l);
      if (m == l) {
        dd[l] = p;
        l = l - 1;
        if (l >= lend) goto qr_top;
        goto blk_done;
      }
      if (m == l - 1) {
        float rt1, rt2, c2, s2;
        slaev2(rlanef(dsn, l - 1), rlanef(esn, l - 1), rlanef(dsn, l), &rt1, &rt2, &c2, &s2);
        if (lane == 0 && nrot < MAXLOG) { logcs[nrot] = make_float2(c2, -s2); logi[nrot] = l - 1; }
        nrot++;
        dd[l - 1] = rt1; dd[l] = rt2; ee[l - 1] = 0.f;
        l -= 2;
        if (l >= lend) goto qr_top;
        goto blk_done;
      }
      if (jtot == nmaxit) goto blk_done;
      jtot++;
      float g = (rlanef(dsn, l - 1) - p) / (2.f * rlanef(esn, l - 1));
      float r = slapy2(g, 1.f);
      g = rlanef(dsn, m) - p + rlanef(esn, l - 1) / (g + ssign(r, g));
      float s = 1.f, c = 1.f;
      p = 0.f;
      for (int i = m; i <= l - 1; ++i) {
        float eI = rlanef(esn, i);
        float f = s * eI;
        float bb = c * eI;
        slartg(g, f, &c, &s, &r);
        if (i != m) ee[i - 1] = r;
        g = rlanef(dsn, i) - p;
        r = (rlanef(dsn, i + 1) - g) * s + 2.f * c * bb;
        p = s * r;
        dd[i] = g + p;
        g = c * r - bb;
        if (lane == 0 && nrot < MAXLOG) { logcs[nrot] = make_float2(c, -s); logi[nrot] = i; }  // QR: sigma=-s
        nrot++;
      }
      dd[l] = rlanef(dsn, l) - p;
      ee[l - 1] = g;
    }
    goto qr_top;
  }
blk_done:
  goto outer;

done:;
  // -------- sign-safe epilogue v4: kmax + replay + back-transform ----------
  // top eigenvalue index (serial scan preserves LAPACK's tie-breaking)
  dsn = dd[row];
  int kmax = 0;
  float dmax = rlanef(dsn, 0);
  for (int j = 1; j < 16; ++j) {
    float dj = rlanef(dsn, j);
    if (dj > dmax) { dmax = dj; kmax = j; }
  }

  // Preload tau column and householder column into registers: statically
  // indexed after unroll -> pure VGPRs; all ~30 ds_reads issue back-to-back
  // with ONE lgkmcnt wait instead of 15 serial dependent pairs.
  float tcol[15], acolr[15];
#pragma unroll
  for (int i2 = 0; i2 < 15; ++i2) {
    tcol[i2] = ttl[lane][i2];
    acolr[i2] = (lane < 16) ? A[lane][i2] : 0.f;   // guard: A is [16][17]
  }

  // pad the rotation log to a multiple of 64 with sentinel i=255: no lane
  // matches, so padded slots apply NO arithmetic to w (exact no-op).
  int cap = nrot < MAXLOG ? nrot : MAXLOG;
  int padded = (cap + 63) & ~63;
  for (int j = cap + lane; j < padded; j += 64) {
    logi[j] = 255;
    logcs[j] = make_float2(1.f, 0.f);
  }

  // reverse replay: w = G_0(G_1(...(G_{n-1} e_kmax)))
  //   (G*w)[i] = c*w[i] + sg*w[i+1]; (G*w)[i+1] = -sg*w[i] + c*w[i+1]
  // Register-batched (one LDS read per 64 rotations; lane k holds rotation
  // base+k) with NEXT-BATCH PREFETCH issued before the unrolled body, so the
  // ~120cy ds_read latency hides under the previous batch's VALU chain.
  float w = (lane == kmax) ? 1.f : 0.f;
  if (padded > 0) {
    int base = padded - 64;
    float2 bcs = logcs[base + lane];
    int bii = logi[base + lane];
    while (base >= 0) {
      int nbase = base - 64;
      float2 ncs = make_float2(1.f, 0.f);
      int nii = 255;
      if (nbase >= 0) { ncs = logcs[nbase + lane]; nii = logi[nbase + lane]; }
#pragma unroll
      for (int k = 63; k >= 0; --k) {
        float c = rlanef(bcs.x, k);
        float sg = rlanef(bcs.y, k);
        int i = __builtin_amdgcn_readlane(bii, k);
        float wdn = dpp_shl1(w);   // w[lane+1]
        float wup = dpp_shr1(w);   // w[lane-1]
        float ca = c * w + sg * wdn;     // candidate for lane == i
        float cb = -sg * wup + c * w;    // candidate for lane == i+1
        w = (lane == i) ? ca : ((lane == i + 1) ? cb : w);
      }
      bcs = ncs; bii = nii; base = nbase;
    }
  }

  float vreg = (lane < 16) ? w : 0.f;
  // back-transform: v := H(0) H(1) ... H(14) v  (apply H(14) first)
  // Fully unrolled on preloaded registers; DPP row-scan reduction.
#pragma unroll
  for (int i = 14; i >= 0; --i) {
    float taui = tcol[i];
    if (taui == 0.f) continue;
    float contrib;
    if (lane == i + 1) contrib = vreg;
    else if (lane >= i + 2 && lane < 16) contrib = acolr[i] * vreg;
    else contrib = 0.f;
    float dot = rowsum16_bcast(contrib);
    float td = taui * dot;
    if (lane == i + 1) vreg -= td;
    else if (lane >= i + 2 && lane < 16) vreg -= td * acolr[i];
  }

  float act = 1.f / (1.f + expf(-(dmax / trace - bias[pid & 31])));
  if (lane == 0) out[pid] = act;
  if (lane < 16) out[512 + pid * 16 + lane] = vreg;
}

extern "C" void kernel_launch(void* const* d_in, const int* in_sizes, int n_in,
                              void* d_out, int out_size, void* d_ws, size_t ws_size,
                              hipStream_t stream) {
  const float* in   = (const float*)d_in[0];   // [16,14,14,544] fp32
  const float* W    = (const float*)d_in[1];   // [1,32,32,4,4] fp32
  const float* bias = (const float*)d_in[2];   // [32] fp32
  float* out = (float*)d_out;

  float* Mbuf = (float*)d_ws;            // 512*256 floats = 512 KB
  float* Gbuf = Mbuf + 512 * 256;        // 512*256 floats = 512 KB

  moments_kernel<<<512, 256, 0, stream>>>(in, Mbuf);
  gram_kernel<<<512, 256, 0, stream>>>(Mbuf, W, Gbuf);
  eig_kernel<<<512, 64, 0, stream>>>(Gbuf, bias, out);
}